// Round 1
// baseline (52.069 us; speedup 1.0000x reference)
//
#include <hip/hip_runtime.h>
#include <cstdint>

#define B_SZ 8192
#define D_SZ 512
#define K_SZ 2048
#define EPSV 1e-8f
// 1/TEMP
#define INV_T 2.0f

typedef float floatx16 __attribute__((ext_vector_type(16)));
typedef int intx8 __attribute__((ext_vector_type(8)));

// async global->LDS, 16B per lane. LDS dest must be wave-uniform base + lane*16.
__device__ __forceinline__ void async_cp16(const void* g, void* l) {
    typedef __attribute__((address_space(1))) unsigned int gds_t;
    typedef __attribute__((address_space(3))) unsigned int lds_t;
    __builtin_amdgcn_global_load_lds((gds_t*)(unsigned long long)g, (lds_t*)l, 16, 0, 0);
}

// pack 8 fp32 -> 8 fp8 e4m3 (OCP, RNE, saturating) as int2
__device__ __forceinline__ int2 pack_fp8x8(float4 a0, float4 a1) {
    int w0 = __builtin_amdgcn_cvt_pk_fp8_f32(a0.x, a0.y, 0, false);
    w0 = __builtin_amdgcn_cvt_pk_fp8_f32(a0.z, a0.w, w0, true);
    int w1 = __builtin_amdgcn_cvt_pk_fp8_f32(a1.x, a1.y, 0, false);
    w1 = __builtin_amdgcn_cvt_pk_fp8_f32(a1.z, a1.w, w1, true);
    return make_int2(w0, w1);
}

// ---------------------------------------------------------------------------
// Kernel 1 (merged prep+gather):
//  blocks [0,2048):  per-row norms of z_i/z_j, positive logit, z_i -> fp8 A.
//    Blocks [0,64) also zero the per-row atomic accumulators rowacc[16384]
//    (harness poisons ws with 0xAA); block 0 zeroes d_out.
//  blocks [2048,3072): gather 2K=4096 rows (c_k, c_k+1) of z_j -> fp8 G +
//    per-column-pair metadata kmeta[k] = {1/nj(c), 1/nj(c+1), c0}.
// ---------------------------------------------------------------------------
__global__ __launch_bounds__(256) void k_prep(
    const float* __restrict__ zi, const float* __restrict__ zj,
    const int* __restrict__ perm,
    float* __restrict__ ri_arr, float* __restrict__ pos_arr,
    unsigned char* __restrict__ A,
    float4* __restrict__ kmeta, unsigned char* __restrict__ G,
    float* __restrict__ rowacc, float* __restrict__ out)
{
    int w = threadIdx.x >> 6, l = threadIdx.x & 63;
    if (blockIdx.x < 2048) {
        if (blockIdx.x < 64)
            rowacc[blockIdx.x * 256 + threadIdx.x] = 0.f;   // pe[8192] ++ pc[8192]
        if (blockIdx.x == 0 && threadIdx.x < 3) out[threadIdx.x] = 0.f;
        int row = blockIdx.x * 4 + w;
        const float4* zi4 = (const float4*)(zi + (size_t)row * D_SZ);
        const float4* zj4 = (const float4*)(zj + (size_t)row * D_SZ);
        float4 a0 = zi4[2 * l], a1 = zi4[2 * l + 1];
        float4 b0 = zj4[2 * l], b1 = zj4[2 * l + 1];
        float si = a0.x * a0.x + a0.y * a0.y + a0.z * a0.z + a0.w * a0.w
                 + a1.x * a1.x + a1.y * a1.y + a1.z * a1.z + a1.w * a1.w;
        float sj = b0.x * b0.x + b0.y * b0.y + b0.z * b0.z + b0.w * b0.w
                 + b1.x * b1.x + b1.y * b1.y + b1.z * b1.z + b1.w * b1.w;
        float dd = a0.x * b0.x + a0.y * b0.y + a0.z * b0.z + a0.w * b0.w
                 + a1.x * b1.x + a1.y * b1.y + a1.z * b1.z + a1.w * b1.w;
        for (int m = 1; m < 64; m <<= 1) {
            si += __shfl_xor(si, m);
            sj += __shfl_xor(sj, m);
            dd += __shfl_xor(dd, m);
        }
        if (l == 0) {
            float ni = sqrtf(si), nj = sqrtf(sj);
            ri_arr[row] = INV_T / fmaxf(ni, 1e-6f);   // norms ~22; eps never binds
            pos_arr[row] = dd / fmaxf(ni * nj, EPSV) * INV_T;
        }
        *(int2*)(A + (size_t)row * D_SZ + l * 8) = pack_fp8x8(a0, a1);
    } else {
        __shared__ float srj[4];
        int g = (blockIdx.x - 2048) * 4 + w;        // 0..4095
        int c0 = perm[g >> 1];
        int c = c0 + (g & 1);                       // actual z_j row
        const float4* src = (const float4*)(zj + (size_t)c * D_SZ);
        float4 a0 = src[2 * l], a1 = src[2 * l + 1];
        float s = a0.x * a0.x + a0.y * a0.y + a0.z * a0.z + a0.w * a0.w
                + a1.x * a1.x + a1.y * a1.y + a1.z * a1.z + a1.w * a1.w;
        for (int m = 1; m < 64; m <<= 1) s += __shfl_xor(s, m);
        if (l == 0) srj[w] = 1.0f / fmaxf(sqrtf(s), 1e-6f);
        __syncthreads();
        if ((w & 1) == 0 && l == 0)
            kmeta[g >> 1] = make_float4(srj[w], srj[w + 1],
                                        __int_as_float(c0), 0.f);
        *(int2*)(G + (size_t)g * D_SZ + l * 8) = pack_fp8x8(a0, a1);
    }
}

// ---------------------------------------------------------------------------
// Kernel 2: MX-fp8 MFMA GEMM, TRANSPOSED OUTPUT: S^T = G . A^T.
// NEW (this round): 256x256 tile, 512 threads (8 waves, 4M x 2N), deep
// pipeline with a 4-deep LDS K-tile ring (4 x (16KB A + 16KB G) = 128 KB)
// and COUNTED vmcnt (T3+T4): the main loop never drains vmcnt to 0 and uses
// raw s_barrier (no __syncthreads vmcnt(0) drain). One barrier per K-step.
//   prologue: stage tiles 0,1,2 (4 gl_lds/wave/tile)
//   iter t:   vmcnt(8) -> tile t landed (t+1,t+2 in flight); s_barrier;
//             stage tile t+3 into buf (t+3)&3 (== buf (t-1)&3, already
//             consumed by all waves -- the barrier proves it);
//             12 ds_read_b128; setprio(1); 8 MFMA 32x32x64 fp8; setprio(0).
// Same 16B-chunk XOR swizzle (slot = c ^ ((r^(r>>2))&3), 0 bank conflicts),
// same fused pair-select epilogue -> per-anchor atomic pe/pc.
// XCD-aware: xcd = bid&7 owns a 512-row G slab (L2-resident).
// ---------------------------------------------------------------------------
__global__ __launch_bounds__(512, 2) void k_gemm(
    const unsigned char* __restrict__ A,    // [8192][512] fp8  (anchors)
    const unsigned char* __restrict__ G,    // [4096][512] fp8  (gathered)
    const float4* __restrict__ kmeta,       // [2048]  {rj0, rj1, c0f, -}
    const float* __restrict__ ri_arr,       // [8192]  INV_T/ni
    const float* __restrict__ pos_arr,      // [8192]
    float* __restrict__ rowacc)             // [2][8192] atomic accumulators
{
    __shared__ unsigned char lds[4][2][16384];   // ring: [buf][0=A,1=G], 128 KB
    const int tid = threadIdx.x;
    const int l = tid & 63, w = tid >> 6;        // 8 waves
    const int wm = w >> 1, wn = w & 1;           // 4 (G-quarters) x 2 (anchor halves)
    const int ln = l & 31, q = l >> 5;           // 32x32 MFMA lane decomposition

    const int bid = blockIdx.x;                  // 512 blocks
    const int xcd = bid & 7;
    const int slot = bid >> 3;                   // 0..63
    const int gTile = xcd * 2 + (slot & 1);      // 0..15 (256-row G panel)
    const int aTile = slot >> 1;                 // 0..31 (256-row anchor panel)
    const int gBase = gTile * 256;
    const int aBase = aTile * 256;

    // staging: per K-tile each array is 1024 16B chunks -> 2 gl_lds per thread
    size_t aOff[2], gOff[2];
    int ldsOff[2];
    #pragma unroll
    for (int it = 0; it < 2; ++it) {
        int fc = it * 512 + tid;                 // chunk 0..1023
        int r = fc >> 2, s = fc & 3;             // row 0..255, slot 0..3
        int scc = s ^ ((r ^ (r >> 2)) & 3);      // XOR-swizzled SOURCE chunk
        aOff[it] = (size_t)(aBase + r) * D_SZ + scc * 16;
        gOff[it] = (size_t)(gBase + r) * D_SZ + scc * 16;
        ldsOff[it] = fc * 16;                    // linear dest: wave base + lane*16
    }

#define STAGE(t_) do {                                                      \
        unsigned char* Ad_ = &lds[(t_) & 3][0][0];                          \
        unsigned char* Gd_ = &lds[(t_) & 3][1][0];                          \
        size_t ko_ = (size_t)(t_) * 64;                                     \
        async_cp16(A + aOff[0] + ko_, Ad_ + ldsOff[0]);                     \
        async_cp16(A + aOff[1] + ko_, Ad_ + ldsOff[1]);                     \
        async_cp16(G + gOff[0] + ko_, Gd_ + ldsOff[0]);                     \
        async_cp16(G + gOff[1] + ko_, Gd_ + ldsOff[1]);                     \
    } while (0)

    // frag read addresses (bytes in a 16 KB region): lane needs k-bytes
    // [q*32, q*32+32) of its row = pre-swizzle chunks {2q, 2q+1}
    int aAddr[4][2], gAddr[2][2];
    #pragma unroll
    for (int tn = 0; tn < 4; ++tn) {
        int ar = wn * 128 + tn * 32 + ln;        // anchor row (N-operand)
        int xa = (ar ^ (ar >> 2)) & 3;
        aAddr[tn][0] = ar * 64 + ((2 * q) ^ xa) * 16;
        aAddr[tn][1] = ar * 64 + ((2 * q + 1) ^ xa) * 16;
    }
    #pragma unroll
    for (int tm = 0; tm < 2; ++tm) {
        int gr = wm * 64 + tm * 32 + ln;         // g row (M-operand)
        int xg = (gr ^ (gr >> 2)) & 3;
        gAddr[tm][0] = gr * 64 + ((2 * q) ^ xg) * 16;
        gAddr[tm][1] = gr * 64 + ((2 * q + 1) ^ xg) * 16;
    }

    floatx16 acc[2][4] = {};                     // [tm: g-subtile][tn: anchor-subtile]

    STAGE(0); STAGE(1); STAGE(2);                // 12 loads/wave in flight

    #pragma unroll 1
    for (int t = 0; t < 8; ++t) {
        // counted vmcnt: tile t's 4 loads are the oldest; keep t+1,t+2 in flight
        if (t < 6)       asm volatile("s_waitcnt vmcnt(8)" ::: "memory");
        else if (t == 6) asm volatile("s_waitcnt vmcnt(4)" ::: "memory");
        else             asm volatile("s_waitcnt vmcnt(0)" ::: "memory");
        __builtin_amdgcn_s_barrier();            // raw barrier: NO vmcnt drain
        __builtin_amdgcn_sched_barrier(0);       // pin: no motion above this point
        if (t < 5) STAGE(t + 3);                 // into buf (t+3)&3 == (t-1)&3
        const unsigned char* Ab = &lds[t & 3][0][0];
        const unsigned char* Gb = &lds[t & 3][1][0];
        intx8 af[4], gf[2];
        #pragma unroll
        for (int tn = 0; tn < 4; ++tn) {
            int4 lo = *(const int4*)(Ab + aAddr[tn][0]);
            int4 hi = *(const int4*)(Ab + aAddr[tn][1]);
            af[tn][0] = lo.x; af[tn][1] = lo.y; af[tn][2] = lo.z; af[tn][3] = lo.w;
            af[tn][4] = hi.x; af[tn][5] = hi.y; af[tn][6] = hi.z; af[tn][7] = hi.w;
        }
        #pragma unroll
        for (int tm = 0; tm < 2; ++tm) {
            int4 lo = *(const int4*)(Gb + gAddr[tm][0]);
            int4 hi = *(const int4*)(Gb + gAddr[tm][1]);
            gf[tm][0] = lo.x; gf[tm][1] = lo.y; gf[tm][2] = lo.z; gf[tm][3] = lo.w;
            gf[tm][4] = hi.x; gf[tm][5] = hi.y; gf[tm][6] = hi.z; gf[tm][7] = hi.w;
        }
        __builtin_amdgcn_s_setprio(1);
        #pragma unroll
        for (int tm = 0; tm < 2; ++tm)
            #pragma unroll
            for (int tn = 0; tn < 4; ++tn)
                acc[tm][tn] = __builtin_amdgcn_mfma_scale_f32_32x32x64_f8f6f4(
                    gf[tm], af[tn], acc[tm][tn],
                    0, 0,                       // cbsz/blgp = fp8 e4m3
                    0, 0x7f7f7f7f,              // scale A: all-ones (2^0)
                    0, 0x7f7f7f7f);             // scale B: all-ones (2^0)
        __builtin_amdgcn_s_setprio(0);
    }
#undef STAGE

    // ---- fused epilogue: pair-select then exp, in-register reduction ----
    // C/D layout (32x32): col = anchor = ln (+tn*32), row = g = (reg&3) +
    // 8*(reg>>2) + 4*q (+tm*32 + wm*64). Regs 4j..4j+3 hold 4 consecutive g,
    // i.e. column pairs k0 = gTile*128 + wm*32 + tm*16 + 4j + 2q and k0+1.
    int anc[4]; float riv[4], pv[4];
    float pe[4] = {0.f, 0.f, 0.f, 0.f}, pc[4] = {0.f, 0.f, 0.f, 0.f};
    #pragma unroll
    for (int tn = 0; tn < 4; ++tn) {
        anc[tn] = aBase + wn * 128 + tn * 32 + ln;
        riv[tn] = ri_arr[anc[tn]];              // INV_T / ni
        pv[tn] = pos_arr[anc[tn]];
    }
    #pragma unroll
    for (int tm = 0; tm < 2; ++tm) {
        #pragma unroll
        for (int j = 0; j < 4; ++j) {
            int k0 = gTile * 128 + wm * 32 + tm * 16 + 4 * j + 2 * q;
            float4 m0 = kmeta[k0];
            float4 m1 = kmeta[k0 + 1];
            #pragma unroll
            for (int p = 0; p < 2; ++p) {
                float4 md = p ? m1 : m0;
                int c0 = __float_as_int(md.z);
                int re = 4 * j + 2 * p;         // even-g reg; odd is re+1
                #pragma unroll
                for (int tn = 0; tn < 4; ++tn) {
                    bool sel = (c0 >= anc[tn]);             // use column c0+1
                    float v = sel ? acc[tm][tn][re + 1] : acc[tm][tn][re];
                    float rj = sel ? md.y : md.x;
                    float logit = v * riv[tn] * rj;
                    pe[tn] += __expf(logit);
                    pc[tn] += (logit > pv[tn]) ? 1.f : 0.f;
                }
            }
        }
    }
    #pragma unroll
    for (int tn = 0; tn < 4; ++tn) {
        pe[tn] += __shfl_xor(pe[tn], 32);
        pc[tn] += __shfl_xor(pc[tn], 32);
        if (q == 0) {
            atomicAdd(&rowacc[anc[tn]], pe[tn]);
            atomicAdd(&rowacc[B_SZ + anc[tn]], pc[tn]);
        }
    }
}

// ---------------------------------------------------------------------------
// Kernel 3: tiny finalize — one thread per row, then block+global reduce.
// 32 blocks x 256 threads; reads only rowacc[2][8192] + pos_arr.
// ---------------------------------------------------------------------------
__global__ __launch_bounds__(256) void k_final(
    const float* __restrict__ rowacc, const float* __restrict__ pos_arr,
    float* __restrict__ out)
{
    int row = blockIdx.x * 256 + threadIdx.x;
    float pe = rowacc[row];
    float pc = rowacc[B_SZ + row];
    float pos = pos_arr[row];
    float loss = logf(__expf(pos) + pe) - pos;   // logsumexp - pos (logits bounded)
    float a1 = (pc < 0.5f) ? 1.f : 0.f;          // no neg strictly > pos
    float a5 = (pc < 4.5f) ? 1.f : 0.f;          // at most 4 negs strictly > pos
    for (int m = 1; m < 64; m <<= 1) {
        loss += __shfl_xor(loss, m);
        a1 += __shfl_xor(a1, m);
        a5 += __shfl_xor(a5, m);
    }
    __shared__ float red[3][4];
    int w = threadIdx.x >> 6, l = threadIdx.x & 63;
    if (l == 0) { red[0][w] = loss; red[1][w] = a1; red[2][w] = a5; }
    __syncthreads();
    if (threadIdx.x == 0) {
        float L = red[0][0] + red[0][1] + red[0][2] + red[0][3];
        float A1 = red[1][0] + red[1][1] + red[1][2] + red[1][3];
        float A5 = red[2][0] + red[2][1] + red[2][2] + red[2][3];
        atomicAdd(&out[0], L / (float)B_SZ);
        atomicAdd(&out[1], A1 * (100.f / (float)B_SZ));
        atomicAdd(&out[2], A5 * (100.f / (float)B_SZ));
    }
}

// ---------------------------------------------------------------------------
extern "C" void kernel_launch(void* const* d_in, const int* in_sizes, int n_in,
                              void* d_out, int out_size, void* d_ws, size_t ws_size,
                              hipStream_t stream)
{
    const float* zi = (const float*)d_in[0];
    const float* zj = (const float*)d_in[1];
    const int* perm = (const int*)d_in[2];
    float* out = (float*)d_out;

    // workspace layout (all 16B aligned)
    char* p = (char*)d_ws;
    unsigned char* A = (unsigned char*)p;    p += (size_t)B_SZ * D_SZ;          // 4 MB
    unsigned char* G = (unsigned char*)p;    p += (size_t)2 * K_SZ * D_SZ;      // 2 MB
    float* ri_arr = (float*)p;               p += (size_t)B_SZ * 4;
    float* pos_arr = (float*)p;              p += (size_t)B_SZ * 4;
    float4* kmeta = (float4*)p;              p += (size_t)K_SZ * 16;            // 32 KB
    float* rowacc = (float*)p;               p += (size_t)2 * B_SZ * 4;         // 64 KB

    k_prep<<<2048 + 1024, 256, 0, stream>>>(zi, zj, perm, ri_arr, pos_arr, A,
                                            kmeta, G, rowacc, out);
    k_gemm<<<512, 512, 0, stream>>>(A, G, kmeta, ri_arr, pos_arr, rowacc);
    k_final<<<32, 256, 0, stream>>>(rowacc, pos_arr, out);
}

// Round 2
// 52.046 us; speedup vs baseline: 1.0005x; 1.0005x over previous
//
#include <hip/hip_runtime.h>
#include <cstdint>

#define B_SZ 8192
#define D_SZ 512
#define K_SZ 2048
#define EPSV 1e-8f
// 1/TEMP
#define INV_T 2.0f

typedef float floatx16 __attribute__((ext_vector_type(16)));
typedef int intx8 __attribute__((ext_vector_type(8)));

// async global->LDS, 16B per lane. LDS dest must be wave-uniform base + lane*16.
__device__ __forceinline__ void async_cp16(const void* g, void* l) {
    typedef __attribute__((address_space(1))) unsigned int gds_t;
    typedef __attribute__((address_space(3))) unsigned int lds_t;
    __builtin_amdgcn_global_load_lds((gds_t*)(unsigned long long)g, (lds_t*)l, 16, 0, 0);
}

// pack 8 fp32 -> 8 fp8 e4m3 (OCP, RNE, saturating) as int2
__device__ __forceinline__ int2 pack_fp8x8(float4 a0, float4 a1) {
    int w0 = __builtin_amdgcn_cvt_pk_fp8_f32(a0.x, a0.y, 0, false);
    w0 = __builtin_amdgcn_cvt_pk_fp8_f32(a0.z, a0.w, w0, true);
    int w1 = __builtin_amdgcn_cvt_pk_fp8_f32(a1.x, a1.y, 0, false);
    w1 = __builtin_amdgcn_cvt_pk_fp8_f32(a1.z, a1.w, w1, true);
    return make_int2(w0, w1);
}

// ---------------------------------------------------------------------------
// Kernel 1 (merged prep+gather):
//  blocks [0,2048):  per-row norms of z_i/z_j, positive logit, z_i -> fp8 A.
//    Blocks [0,64) also zero the per-row atomic accumulators rowacc[16384]
//    (harness poisons ws with 0xAA); block 0 zeroes d_out.
//  blocks [2048,3072): gather 2K=4096 rows (c_k, c_k+1) of z_j -> fp8 G +
//    per-column-pair metadata kmeta[k] = {1/nj(c), 1/nj(c+1), c0}.
// ---------------------------------------------------------------------------
__global__ __launch_bounds__(256) void k_prep(
    const float* __restrict__ zi, const float* __restrict__ zj,
    const int* __restrict__ perm,
    float* __restrict__ ri_arr, float* __restrict__ pos_arr,
    unsigned char* __restrict__ A,
    float4* __restrict__ kmeta, unsigned char* __restrict__ G,
    float* __restrict__ rowacc, float* __restrict__ out)
{
    int w = threadIdx.x >> 6, l = threadIdx.x & 63;
    if (blockIdx.x < 2048) {
        if (blockIdx.x < 64)
            rowacc[blockIdx.x * 256 + threadIdx.x] = 0.f;   // pe[8192] ++ pc[8192]
        if (blockIdx.x == 0 && threadIdx.x < 3) out[threadIdx.x] = 0.f;
        int row = blockIdx.x * 4 + w;
        const float4* zi4 = (const float4*)(zi + (size_t)row * D_SZ);
        const float4* zj4 = (const float4*)(zj + (size_t)row * D_SZ);
        float4 a0 = zi4[2 * l], a1 = zi4[2 * l + 1];
        float4 b0 = zj4[2 * l], b1 = zj4[2 * l + 1];
        float si = a0.x * a0.x + a0.y * a0.y + a0.z * a0.z + a0.w * a0.w
                 + a1.x * a1.x + a1.y * a1.y + a1.z * a1.z + a1.w * a1.w;
        float sj = b0.x * b0.x + b0.y * b0.y + b0.z * b0.z + b0.w * b0.w
                 + b1.x * b1.x + b1.y * b1.y + b1.z * b1.z + b1.w * b1.w;
        float dd = a0.x * b0.x + a0.y * b0.y + a0.z * b0.z + a0.w * b0.w
                 + a1.x * b1.x + a1.y * b1.y + a1.z * b1.z + a1.w * b1.w;
        for (int m = 1; m < 64; m <<= 1) {
            si += __shfl_xor(si, m);
            sj += __shfl_xor(sj, m);
            dd += __shfl_xor(dd, m);
        }
        if (l == 0) {
            float ni = sqrtf(si), nj = sqrtf(sj);
            ri_arr[row] = INV_T / fmaxf(ni, 1e-6f);   // norms ~22; eps never binds
            pos_arr[row] = dd / fmaxf(ni * nj, EPSV) * INV_T;
        }
        *(int2*)(A + (size_t)row * D_SZ + l * 8) = pack_fp8x8(a0, a1);
    } else {
        __shared__ float srj[4];
        int g = (blockIdx.x - 2048) * 4 + w;        // 0..4095
        int c0 = perm[g >> 1];
        int c = c0 + (g & 1);                       // actual z_j row
        const float4* src = (const float4*)(zj + (size_t)c * D_SZ);
        float4 a0 = src[2 * l], a1 = src[2 * l + 1];
        float s = a0.x * a0.x + a0.y * a0.y + a0.z * a0.z + a0.w * a0.w
                + a1.x * a1.x + a1.y * a1.y + a1.z * a1.z + a1.w * a1.w;
        for (int m = 1; m < 64; m <<= 1) s += __shfl_xor(s, m);
        if (l == 0) srj[w] = 1.0f / fmaxf(sqrtf(s), 1e-6f);
        __syncthreads();
        if ((w & 1) == 0 && l == 0)
            kmeta[g >> 1] = make_float4(srj[w], srj[w + 1],
                                        __int_as_float(c0), 0.f);
        *(int2*)(G + (size_t)g * D_SZ + l * 8) = pack_fp8x8(a0, a1);
    }
}

// ---------------------------------------------------------------------------
// Kernel 2: MX-fp8 MFMA GEMM, TRANSPOSED OUTPUT: S^T = G . A^T.
// R2: same 256x256 / 512-thread / 4-deep-ring skeleton as R1 (verified
// correct), but the K-loop now uses the m201-style PHASED schedule:
// per K-tile two {barrier -> lgkm -> setprio -> 4-MFMA} phases with the
// 12 ds_reads + staging issued up front, so ds-latency and the t+3
// prefetch hide under the MFMA clusters, and the counted-vmcnt gate for
// tile t+1 sits just before the tile's LAST barrier (the barrier then
// proves all waves' t+1 loads landed -- no extra barrier, never drains
// to 0 in the main loop). 3 barriers per K-tile, 524 kFLOP per MFMA
// phase (matches m201's phase granularity).
// Same 16B-chunk XOR swizzle (slot = c ^ ((r^(r>>2))&3), 0 bank conflicts),
// same fused pair-select epilogue -> per-anchor atomic pe/pc.
// XCD-aware: xcd = bid&7 owns a 512-row G slab (L2-resident).
// ---------------------------------------------------------------------------
__global__ __launch_bounds__(512, 2) void k_gemm(
    const unsigned char* __restrict__ A,    // [8192][512] fp8  (anchors)
    const unsigned char* __restrict__ G,    // [4096][512] fp8  (gathered)
    const float4* __restrict__ kmeta,       // [2048]  {rj0, rj1, c0f, -}
    const float* __restrict__ ri_arr,       // [8192]  INV_T/ni
    const float* __restrict__ pos_arr,      // [8192]
    float* __restrict__ rowacc)             // [2][8192] atomic accumulators
{
    __shared__ unsigned char lds[4][2][16384];   // ring: [buf][0=A,1=G], 128 KB
    const int tid = threadIdx.x;
    const int l = tid & 63, w = tid >> 6;        // 8 waves
    const int wm = w >> 1, wn = w & 1;           // 4 (G-quarters) x 2 (anchor halves)
    const int ln = l & 31, q = l >> 5;           // 32x32 MFMA lane decomposition

    const int bid = blockIdx.x;                  // 512 blocks
    const int xcd = bid & 7;
    const int slot = bid >> 3;                   // 0..63
    const int gTile = xcd * 2 + (slot & 1);      // 0..15 (256-row G panel)
    const int aTile = slot >> 1;                 // 0..31 (256-row anchor panel)
    const int gBase = gTile * 256;
    const int aBase = aTile * 256;

    // staging: per K-tile each array is 1024 16B chunks -> 2 gl_lds per thread
    size_t aOff[2], gOff[2];
    int ldsOff[2];
    #pragma unroll
    for (int it = 0; it < 2; ++it) {
        int fc = it * 512 + tid;                 // chunk 0..1023
        int r = fc >> 2, s = fc & 3;             // row 0..255, slot 0..3
        int scc = s ^ ((r ^ (r >> 2)) & 3);      // XOR-swizzled SOURCE chunk
        aOff[it] = (size_t)(aBase + r) * D_SZ + scc * 16;
        gOff[it] = (size_t)(gBase + r) * D_SZ + scc * 16;
        ldsOff[it] = fc * 16;                    // linear dest: wave base + lane*16
    }

#define STAGE_A(t_) do {                                                    \
        unsigned char* Ad_ = &lds[(t_) & 3][0][0];                          \
        size_t ko_ = (size_t)(t_) * 64;                                     \
        async_cp16(A + aOff[0] + ko_, Ad_ + ldsOff[0]);                     \
        async_cp16(A + aOff[1] + ko_, Ad_ + ldsOff[1]);                     \
    } while (0)
#define STAGE_G(t_) do {                                                    \
        unsigned char* Gd_ = &lds[(t_) & 3][1][0];                          \
        size_t ko_ = (size_t)(t_) * 64;                                     \
        async_cp16(G + gOff[0] + ko_, Gd_ + ldsOff[0]);                     \
        async_cp16(G + gOff[1] + ko_, Gd_ + ldsOff[1]);                     \
    } while (0)

    // frag read addresses (bytes in a 16 KB region): lane needs k-bytes
    // [q*32, q*32+32) of its row = pre-swizzle chunks {2q, 2q+1}
    int aAddr[4][2], gAddr[2][2];
    #pragma unroll
    for (int tn = 0; tn < 4; ++tn) {
        int ar = wn * 128 + tn * 32 + ln;        // anchor row (N-operand)
        int xa = (ar ^ (ar >> 2)) & 3;
        aAddr[tn][0] = ar * 64 + ((2 * q) ^ xa) * 16;
        aAddr[tn][1] = ar * 64 + ((2 * q + 1) ^ xa) * 16;
    }
    #pragma unroll
    for (int tm = 0; tm < 2; ++tm) {
        int gr = wm * 64 + tm * 32 + ln;         // g row (M-operand)
        int xg = (gr ^ (gr >> 2)) & 3;
        gAddr[tm][0] = gr * 64 + ((2 * q) ^ xg) * 16;
        gAddr[tm][1] = gr * 64 + ((2 * q + 1) ^ xg) * 16;
    }

    floatx16 acc[2][4] = {};                     // [tm: g-subtile][tn: anchor-subtile]

    // prologue: stage tiles 0,1,2 (12 loads/thread in flight), then gate
    // tile 0 (own loads landed + barrier => everyone's landed).
    STAGE_A(0); STAGE_G(0);
    STAGE_A(1); STAGE_G(1);
    STAGE_A(2); STAGE_G(2);
    asm volatile("s_waitcnt vmcnt(8)" ::: "memory");
    __builtin_amdgcn_sched_barrier(0);
    __builtin_amdgcn_s_barrier();
    __builtin_amdgcn_sched_barrier(0);

    #pragma unroll 1
    for (int t = 0; t < 8; ++t) {
        const unsigned char* Ab = &lds[t & 3][0][0];
        const unsigned char* Gb = &lds[t & 3][1][0];
        // ---- issue all 12 ds_reads (af first, then gf0, gf1) + A-stage ----
        intx8 af[4], gf[2];
        #pragma unroll
        for (int tn = 0; tn < 4; ++tn) {
            int4 lo = *(const int4*)(Ab + aAddr[tn][0]);
            int4 hi = *(const int4*)(Ab + aAddr[tn][1]);
            af[tn][0] = lo.x; af[tn][1] = lo.y; af[tn][2] = lo.z; af[tn][3] = lo.w;
            af[tn][4] = hi.x; af[tn][5] = hi.y; af[tn][6] = hi.z; af[tn][7] = hi.w;
        }
        #pragma unroll
        for (int tm = 0; tm < 2; ++tm) {
            int4 lo = *(const int4*)(Gb + gAddr[tm][0]);
            int4 hi = *(const int4*)(Gb + gAddr[tm][1]);
            gf[tm][0] = lo.x; gf[tm][1] = lo.y; gf[tm][2] = lo.z; gf[tm][3] = lo.w;
            gf[tm][4] = hi.x; gf[tm][5] = hi.y; gf[tm][6] = hi.z; gf[tm][7] = hi.w;
        }
        if (t < 5) STAGE_A(t + 3);               // prefetch into buf (t-1)&3
        // ---- phase A: MFMA group tm=0 (needs af[0..3], gf[0] only) ----
        __builtin_amdgcn_sched_barrier(0);
        __builtin_amdgcn_s_barrier();
        __builtin_amdgcn_sched_barrier(0);
        __builtin_amdgcn_s_setprio(1);
        #pragma unroll
        for (int tn = 0; tn < 4; ++tn)
            acc[0][tn] = __builtin_amdgcn_mfma_scale_f32_32x32x64_f8f6f4(
                gf[0], af[tn], acc[0][tn],
                0, 0, 0, 0x7f7f7f7f, 0, 0x7f7f7f7f);
        __builtin_amdgcn_s_setprio(0);
        if (t < 5) STAGE_G(t + 3);
        // ---- phase B: MFMA group tm=1 (gf[1] had phase A to land) ----
        __builtin_amdgcn_sched_barrier(0);
        __builtin_amdgcn_s_barrier();
        __builtin_amdgcn_sched_barrier(0);
        __builtin_amdgcn_s_setprio(1);
        #pragma unroll
        for (int tn = 0; tn < 4; ++tn)
            acc[1][tn] = __builtin_amdgcn_mfma_scale_f32_32x32x64_f8f6f4(
                gf[1], af[tn], acc[1][tn],
                0, 0, 0, 0x7f7f7f7f, 0, 0x7f7f7f7f);
        __builtin_amdgcn_s_setprio(0);
        // ---- counted vmcnt gate for tile t+1, fused into the tile's last
        // barrier: after it, ALL waves' t+1 loads have landed. Keeps 8 loads
        // (tiles t+2,t+3) in flight in steady state; drains 8->4->0 in tail.
        if (t < 5)       asm volatile("s_waitcnt vmcnt(8)" ::: "memory");
        else if (t == 5) asm volatile("s_waitcnt vmcnt(4)" ::: "memory");
        else if (t == 6) asm volatile("s_waitcnt vmcnt(0)" ::: "memory");
        __builtin_amdgcn_sched_barrier(0);
        __builtin_amdgcn_s_barrier();
        __builtin_amdgcn_sched_barrier(0);
    }
#undef STAGE_A
#undef STAGE_G

    // ---- fused epilogue: pair-select then exp, in-register reduction ----
    // C/D layout (32x32): col = anchor = ln (+tn*32), row = g = (reg&3) +
    // 8*(reg>>2) + 4*q (+tm*32 + wm*64). Regs 4j..4j+3 hold 4 consecutive g,
    // i.e. column pairs k0 = gTile*128 + wm*32 + tm*16 + 4j + 2q and k0+1.
    int anc[4]; float riv[4], pv[4];
    float pe[4] = {0.f, 0.f, 0.f, 0.f}, pc[4] = {0.f, 0.f, 0.f, 0.f};
    #pragma unroll
    for (int tn = 0; tn < 4; ++tn) {
        anc[tn] = aBase + wn * 128 + tn * 32 + ln;
        riv[tn] = ri_arr[anc[tn]];              // INV_T / ni
        pv[tn] = pos_arr[anc[tn]];
    }
    #pragma unroll
    for (int tm = 0; tm < 2; ++tm) {
        #pragma unroll
        for (int j = 0; j < 4; ++j) {
            int k0 = gTile * 128 + wm * 32 + tm * 16 + 4 * j + 2 * q;
            float4 m0 = kmeta[k0];
            float4 m1 = kmeta[k0 + 1];
            #pragma unroll
            for (int p = 0; p < 2; ++p) {
                float4 md = p ? m1 : m0;
                int c0 = __float_as_int(md.z);
                int re = 4 * j + 2 * p;         // even-g reg; odd is re+1
                #pragma unroll
                for (int tn = 0; tn < 4; ++tn) {
                    bool sel = (c0 >= anc[tn]);             // use column c0+1
                    float v = sel ? acc[tm][tn][re + 1] : acc[tm][tn][re];
                    float rj = sel ? md.y : md.x;
                    float logit = v * riv[tn] * rj;
                    pe[tn] += __expf(logit);
                    pc[tn] += (logit > pv[tn]) ? 1.f : 0.f;
                }
            }
        }
    }
    #pragma unroll
    for (int tn = 0; tn < 4; ++tn) {
        pe[tn] += __shfl_xor(pe[tn], 32);
        pc[tn] += __shfl_xor(pc[tn], 32);
        if (q == 0) {
            atomicAdd(&rowacc[anc[tn]], pe[tn]);
            atomicAdd(&rowacc[B_SZ + anc[tn]], pc[tn]);
        }
    }
}

// ---------------------------------------------------------------------------
// Kernel 3: tiny finalize — one thread per row, then block+global reduce.
// 32 blocks x 256 threads; reads only rowacc[2][8192] + pos_arr.
// ---------------------------------------------------------------------------
__global__ __launch_bounds__(256) void k_final(
    const float* __restrict__ rowacc, const float* __restrict__ pos_arr,
    float* __restrict__ out)
{
    int row = blockIdx.x * 256 + threadIdx.x;
    float pe = rowacc[row];
    float pc = rowacc[B_SZ + row];
    float pos = pos_arr[row];
    float loss = logf(__expf(pos) + pe) - pos;   // logsumexp - pos (logits bounded)
    float a1 = (pc < 0.5f) ? 1.f : 0.f;          // no neg strictly > pos
    float a5 = (pc < 4.5f) ? 1.f : 0.f;          // at most 4 negs strictly > pos
    for (int m = 1; m < 64; m <<= 1) {
        loss += __shfl_xor(loss, m);
        a1 += __shfl_xor(a1, m);
        a5 += __shfl_xor(a5, m);
    }
    __shared__ float red[3][4];
    int w = threadIdx.x >> 6, l = threadIdx.x & 63;
    if (l == 0) { red[0][w] = loss; red[1][w] = a1; red[2][w] = a5; }
    __syncthreads();
    if (threadIdx.x == 0) {
        float L = red[0][0] + red[0][1] + red[0][2] + red[0][3];
        float A1 = red[1][0] + red[1][1] + red[1][2] + red[1][3];
        float A5 = red[2][0] + red[2][1] + red[2][2] + red[2][3];
        atomicAdd(&out[0], L / (float)B_SZ);
        atomicAdd(&out[1], A1 * (100.f / (float)B_SZ));
        atomicAdd(&out[2], A5 * (100.f / (float)B_SZ));
    }
}

// ---------------------------------------------------------------------------
extern "C" void kernel_launch(void* const* d_in, const int* in_sizes, int n_in,
                              void* d_out, int out_size, void* d_ws, size_t ws_size,
                              hipStream_t stream)
{
    const float* zi = (const float*)d_in[0];
    const float* zj = (const float*)d_in[1];
    const int* perm = (const int*)d_in[2];
    float* out = (float*)d_out;

    // workspace layout (all 16B aligned)
    char* p = (char*)d_ws;
    unsigned char* A = (unsigned char*)p;    p += (size_t)B_SZ * D_SZ;          // 4 MB
    unsigned char* G = (unsigned char*)p;    p += (size_t)2 * K_SZ * D_SZ;      // 2 MB
    float* ri_arr = (float*)p;               p += (size_t)B_SZ * 4;
    float* pos_arr = (float*)p;              p += (size_t)B_SZ * 4;
    float4* kmeta = (float4*)p;              p += (size_t)K_SZ * 16;            // 32 KB
    float* rowacc = (float*)p;               p += (size_t)2 * B_SZ * 4;         // 64 KB

    k_prep<<<2048 + 1024, 256, 0, stream>>>(zi, zj, perm, ri_arr, pos_arr, A,
                                            kmeta, G, rowacc, out);
    k_gemm<<<512, 512, 0, stream>>>(A, G, kmeta, ri_arr, pos_arr, rowacc);
    k_final<<<32, 256, 0, stream>>>(rowacc, pos_arr, out);
}

// Round 3
// 49.921 us; speedup vs baseline: 1.0430x; 1.0426x over previous
//
#include <hip/hip_runtime.h>
#include <cstdint>

#define B_SZ 8192
#define D_SZ 512
#define K_SZ 2048
#define EPSV 1e-8f
// 1/TEMP
#define INV_T 2.0f

typedef float floatx16 __attribute__((ext_vector_type(16)));
typedef int intx8 __attribute__((ext_vector_type(8)));

// async global->LDS, 16B per lane. LDS dest must be wave-uniform base + lane*16.
__device__ __forceinline__ void async_cp16(const void* g, void* l) {
    typedef __attribute__((address_space(1))) unsigned int gds_t;
    typedef __attribute__((address_space(3))) unsigned int lds_t;
    __builtin_amdgcn_global_load_lds((gds_t*)(unsigned long long)g, (lds_t*)l, 16, 0, 0);
}

// raw ds_read_b128 on a 32-bit LDS byte address. Deliberately OPAQUE to the
// compiler: no compiler-visible LDS dependency on global_load_lds, so hipcc
// cannot insert its conservative `s_waitcnt vmcnt(0)` before the reads (the
// R1/R2 serializer). ALL ordering is manual: counted vmcnt gates + lgkmcnt(0)
// + sched_barrier(0) per rule #18.
__device__ __forceinline__ int4 ds_read_b128_asm(unsigned int addr) {
    int4 r;
    asm volatile("ds_read_b128 %0, %1" : "=v"(r) : "v"(addr));
    return r;
}

// pack 8 fp32 -> 8 fp8 e4m3 (OCP, RNE, saturating) as int2
__device__ __forceinline__ int2 pack_fp8x8(float4 a0, float4 a1) {
    int w0 = __builtin_amdgcn_cvt_pk_fp8_f32(a0.x, a0.y, 0, false);
    w0 = __builtin_amdgcn_cvt_pk_fp8_f32(a0.z, a0.w, w0, true);
    int w1 = __builtin_amdgcn_cvt_pk_fp8_f32(a1.x, a1.y, 0, false);
    w1 = __builtin_amdgcn_cvt_pk_fp8_f32(a1.z, a1.w, w1, true);
    return make_int2(w0, w1);
}

// ---------------------------------------------------------------------------
// Kernel 1 (merged prep+gather):
//  blocks [0,2048):  per-row norms of z_i/z_j, positive logit, z_i -> fp8 A.
//    Blocks [0,64) also zero the per-row atomic accumulators rowacc[16384]
//    (harness poisons ws with 0xAA); block 0 zeroes d_out.
//  blocks [2048,3072): gather 2K=4096 rows (c_k, c_k+1) of z_j -> fp8 G +
//    per-column-pair metadata kmeta[k] = {1/nj(c), 1/nj(c+1), c0}.
// ---------------------------------------------------------------------------
__global__ __launch_bounds__(256) void k_prep(
    const float* __restrict__ zi, const float* __restrict__ zj,
    const int* __restrict__ perm,
    float* __restrict__ ri_arr, float* __restrict__ pos_arr,
    unsigned char* __restrict__ A,
    float4* __restrict__ kmeta, unsigned char* __restrict__ G,
    float* __restrict__ rowacc, float* __restrict__ out)
{
    int w = threadIdx.x >> 6, l = threadIdx.x & 63;
    if (blockIdx.x < 2048) {
        if (blockIdx.x < 64)
            rowacc[blockIdx.x * 256 + threadIdx.x] = 0.f;   // pe[8192] ++ pc[8192]
        if (blockIdx.x == 0 && threadIdx.x < 3) out[threadIdx.x] = 0.f;
        int row = blockIdx.x * 4 + w;
        const float4* zi4 = (const float4*)(zi + (size_t)row * D_SZ);
        const float4* zj4 = (const float4*)(zj + (size_t)row * D_SZ);
        float4 a0 = zi4[2 * l], a1 = zi4[2 * l + 1];
        float4 b0 = zj4[2 * l], b1 = zj4[2 * l + 1];
        float si = a0.x * a0.x + a0.y * a0.y + a0.z * a0.z + a0.w * a0.w
                 + a1.x * a1.x + a1.y * a1.y + a1.z * a1.z + a1.w * a1.w;
        float sj = b0.x * b0.x + b0.y * b0.y + b0.z * b0.z + b0.w * b0.w
                 + b1.x * b1.x + b1.y * b1.y + b1.z * b1.z + b1.w * b1.w;
        float dd = a0.x * b0.x + a0.y * b0.y + a0.z * b0.z + a0.w * b0.w
                 + a1.x * b1.x + a1.y * b1.y + a1.z * b1.z + a1.w * b1.w;
        for (int m = 1; m < 64; m <<= 1) {
            si += __shfl_xor(si, m);
            sj += __shfl_xor(sj, m);
            dd += __shfl_xor(dd, m);
        }
        if (l == 0) {
            float ni = sqrtf(si), nj = sqrtf(sj);
            ri_arr[row] = INV_T / fmaxf(ni, 1e-6f);   // norms ~22; eps never binds
            pos_arr[row] = dd / fmaxf(ni * nj, EPSV) * INV_T;
        }
        *(int2*)(A + (size_t)row * D_SZ + l * 8) = pack_fp8x8(a0, a1);
    } else {
        __shared__ float srj[4];
        int g = (blockIdx.x - 2048) * 4 + w;        // 0..4095
        int c0 = perm[g >> 1];
        int c = c0 + (g & 1);                       // actual z_j row
        const float4* src = (const float4*)(zj + (size_t)c * D_SZ);
        float4 a0 = src[2 * l], a1 = src[2 * l + 1];
        float s = a0.x * a0.x + a0.y * a0.y + a0.z * a0.z + a0.w * a0.w
                + a1.x * a1.x + a1.y * a1.y + a1.z * a1.z + a1.w * a1.w;
        for (int m = 1; m < 64; m <<= 1) s += __shfl_xor(s, m);
        if (l == 0) srj[w] = 1.0f / fmaxf(sqrtf(s), 1e-6f);
        __syncthreads();
        if ((w & 1) == 0 && l == 0)
            kmeta[g >> 1] = make_float4(srj[w], srj[w + 1],
                                        __int_as_float(c0), 0.f);
        *(int2*)(G + (size_t)g * D_SZ + l * 8) = pack_fp8x8(a0, a1);
    }
}

// ---------------------------------------------------------------------------
// Kernel 2: MX-fp8 MFMA GEMM, TRANSPOSED OUTPUT: S^T = G . A^T.
// R3: same 256x256 / 512-thread / 4-deep-ring geometry as R1/R2 (verified
// correct), but LDS reads are now inline-asm ds_read_b128 (opaque to the
// compiler) so hipcc cannot insert vmcnt(0) drains before them -- the
// hypothesized R1/R2 pipeline-collapse cause. Per K-tile (one barrier):
//   [tile t resident, waves synced]
//   STAGE(t+3) -> 12 asm ds_reads of tile t -> lgkmcnt(0)+sched_barrier
//   -> setprio(1) 8 MFMA setprio(0)
//   -> counted vmcnt gate for tile t+1 (8/4/0, never 0 till tail)
//   -> s_barrier.
// The lgkmcnt(0) before MFMA also proves all reads of buf t are complete
// before the end barrier, so STAGE(t+4) at iter t+1 may rewrite buf (t)&3's
// ring-distance-4 slot safely.
// Same 16B-chunk XOR swizzle (0 bank conflicts), same fused pair-select
// epilogue -> per-anchor atomic pe/pc. XCD-aware G-slab mapping.
// ---------------------------------------------------------------------------
__global__ __launch_bounds__(512, 2) void k_gemm(
    const unsigned char* __restrict__ A,    // [8192][512] fp8  (anchors)
    const unsigned char* __restrict__ G,    // [4096][512] fp8  (gathered)
    const float4* __restrict__ kmeta,       // [2048]  {rj0, rj1, c0f, -}
    const float* __restrict__ ri_arr,       // [8192]  INV_T/ni
    const float* __restrict__ pos_arr,      // [8192]
    float* __restrict__ rowacc)             // [2][8192] atomic accumulators
{
    __shared__ unsigned char lds[4][2][16384];   // ring: [buf][0=A,1=G], 128 KB
    const int tid = threadIdx.x;
    const int l = tid & 63, w = tid >> 6;        // 8 waves
    const int wm = w >> 1, wn = w & 1;           // 4 (G-quarters) x 2 (anchor halves)
    const int ln = l & 31, q = l >> 5;           // 32x32 MFMA lane decomposition

    const int bid = blockIdx.x;                  // 512 blocks
    const int xcd = bid & 7;
    const int slot = bid >> 3;                   // 0..63
    const int gTile = xcd * 2 + (slot & 1);      // 0..15 (256-row G panel)
    const int aTile = slot >> 1;                 // 0..31 (256-row anchor panel)
    const int gBase = gTile * 256;
    const int aBase = aTile * 256;

    // 32-bit LDS base address for raw ds_read addressing
    typedef __attribute__((address_space(3))) unsigned char lds_u8;
    const unsigned int ldsBase =
        (unsigned int)(unsigned long long)(lds_u8*)&lds[0][0][0];

    // staging: per K-tile each array is 1024 16B chunks -> 2 gl_lds per thread
    size_t aOff[2], gOff[2];
    int ldsOff[2];
    #pragma unroll
    for (int it = 0; it < 2; ++it) {
        int fc = it * 512 + tid;                 // chunk 0..1023
        int r = fc >> 2, s = fc & 3;             // row 0..255, slot 0..3
        int scc = s ^ ((r ^ (r >> 2)) & 3);      // XOR-swizzled SOURCE chunk
        aOff[it] = (size_t)(aBase + r) * D_SZ + scc * 16;
        gOff[it] = (size_t)(gBase + r) * D_SZ + scc * 16;
        ldsOff[it] = fc * 16;                    // linear dest: wave base + lane*16
    }

#define STAGE(t_) do {                                                      \
        unsigned char* Ad_ = &lds[(t_) & 3][0][0];                          \
        unsigned char* Gd_ = &lds[(t_) & 3][1][0];                          \
        size_t ko_ = (size_t)(t_) * 64;                                     \
        async_cp16(A + aOff[0] + ko_, Ad_ + ldsOff[0]);                     \
        async_cp16(A + aOff[1] + ko_, Ad_ + ldsOff[1]);                     \
        async_cp16(G + gOff[0] + ko_, Gd_ + ldsOff[0]);                     \
        async_cp16(G + gOff[1] + ko_, Gd_ + ldsOff[1]);                     \
    } while (0)

    // frag read addresses (bytes in a 16 KB region): lane needs k-bytes
    // [q*32, q*32+32) of its row = pre-swizzle chunks {2q, 2q+1}
    int aAddr[4][2], gAddr[2][2];
    #pragma unroll
    for (int tn = 0; tn < 4; ++tn) {
        int ar = wn * 128 + tn * 32 + ln;        // anchor row (N-operand)
        int xa = (ar ^ (ar >> 2)) & 3;
        aAddr[tn][0] = ar * 64 + ((2 * q) ^ xa) * 16;
        aAddr[tn][1] = ar * 64 + ((2 * q + 1) ^ xa) * 16;
    }
    #pragma unroll
    for (int tm = 0; tm < 2; ++tm) {
        int gr = wm * 64 + tm * 32 + ln;         // g row (M-operand)
        int xg = (gr ^ (gr >> 2)) & 3;
        gAddr[tm][0] = gr * 64 + ((2 * q) ^ xg) * 16;
        gAddr[tm][1] = gr * 64 + ((2 * q + 1) ^ xg) * 16;
    }

    floatx16 acc[2][4] = {};                     // [tm: g-subtile][tn: anchor-subtile]

    // prologue: stage tiles 0,1,2 (12 loads/thread in flight), then gate
    // tile 0 (own loads landed + barrier => everyone's landed).
    STAGE(0); STAGE(1); STAGE(2);
    asm volatile("s_waitcnt vmcnt(8)" ::: "memory");
    __builtin_amdgcn_sched_barrier(0);
    __builtin_amdgcn_s_barrier();
    __builtin_amdgcn_sched_barrier(0);

    #pragma unroll 1
    for (int t = 0; t < 8; ++t) {
        if (t < 5) STAGE(t + 3);                 // prefetch into buf (t-1)&3
        // ---- 12 opaque ds_read_b128 of tile t ----
        const unsigned int bufA = ldsBase + (unsigned int)(t & 3) * 32768u;
        const unsigned int bufG = bufA + 16384u;
        int4 aLo[4], aHi[4], gLo[2], gHi[2];
        #pragma unroll
        for (int tn = 0; tn < 4; ++tn) {
            aLo[tn] = ds_read_b128_asm(bufA + (unsigned int)aAddr[tn][0]);
            aHi[tn] = ds_read_b128_asm(bufA + (unsigned int)aAddr[tn][1]);
        }
        #pragma unroll
        for (int tm = 0; tm < 2; ++tm) {
            gLo[tm] = ds_read_b128_asm(bufG + (unsigned int)gAddr[tm][0]);
            gHi[tm] = ds_read_b128_asm(bufG + (unsigned int)gAddr[tm][1]);
        }
        asm volatile("s_waitcnt lgkmcnt(0)" ::: "memory");
        __builtin_amdgcn_sched_barrier(0);       // rule #18: pin MFMA below wait
        intx8 af[4], gf[2];
        #pragma unroll
        for (int tn = 0; tn < 4; ++tn) {
            af[tn][0] = aLo[tn].x; af[tn][1] = aLo[tn].y;
            af[tn][2] = aLo[tn].z; af[tn][3] = aLo[tn].w;
            af[tn][4] = aHi[tn].x; af[tn][5] = aHi[tn].y;
            af[tn][6] = aHi[tn].z; af[tn][7] = aHi[tn].w;
        }
        #pragma unroll
        for (int tm = 0; tm < 2; ++tm) {
            gf[tm][0] = gLo[tm].x; gf[tm][1] = gLo[tm].y;
            gf[tm][2] = gLo[tm].z; gf[tm][3] = gLo[tm].w;
            gf[tm][4] = gHi[tm].x; gf[tm][5] = gHi[tm].y;
            gf[tm][6] = gHi[tm].z; gf[tm][7] = gHi[tm].w;
        }
        __builtin_amdgcn_s_setprio(1);
        #pragma unroll
        for (int tm = 0; tm < 2; ++tm)
            #pragma unroll
            for (int tn = 0; tn < 4; ++tn)
                acc[tm][tn] = __builtin_amdgcn_mfma_scale_f32_32x32x64_f8f6f4(
                    gf[tm], af[tn], acc[tm][tn],
                    0, 0, 0, 0x7f7f7f7f, 0, 0x7f7f7f7f);
        __builtin_amdgcn_s_setprio(0);
        // ---- counted vmcnt gate for tile t+1, fused into the tile barrier:
        // after it, ALL waves' t+1 loads have landed. Keeps 8 loads (tiles
        // t+2,t+3) in flight in steady state; drains 8->4->0 in tail.
        if (t < 5)       asm volatile("s_waitcnt vmcnt(8)" ::: "memory");
        else if (t == 5) asm volatile("s_waitcnt vmcnt(4)" ::: "memory");
        else if (t == 6) asm volatile("s_waitcnt vmcnt(0)" ::: "memory");
        __builtin_amdgcn_sched_barrier(0);
        __builtin_amdgcn_s_barrier();
        __builtin_amdgcn_sched_barrier(0);
    }
#undef STAGE

    // ---- fused epilogue: pair-select then exp, in-register reduction ----
    // C/D layout (32x32): col = anchor = ln (+tn*32), row = g = (reg&3) +
    // 8*(reg>>2) + 4*q (+tm*32 + wm*64). Regs 4j..4j+3 hold 4 consecutive g,
    // i.e. column pairs k0 = gTile*128 + wm*32 + tm*16 + 4j + 2q and k0+1.
    int anc[4]; float riv[4], pv[4];
    float pe[4] = {0.f, 0.f, 0.f, 0.f}, pc[4] = {0.f, 0.f, 0.f, 0.f};
    #pragma unroll
    for (int tn = 0; tn < 4; ++tn) {
        anc[tn] = aBase + wn * 128 + tn * 32 + ln;
        riv[tn] = ri_arr[anc[tn]];              // INV_T / ni
        pv[tn] = pos_arr[anc[tn]];
    }
    #pragma unroll
    for (int tm = 0; tm < 2; ++tm) {
        #pragma unroll
        for (int j = 0; j < 4; ++j) {
            int k0 = gTile * 128 + wm * 32 + tm * 16 + 4 * j + 2 * q;
            float4 m0 = kmeta[k0];
            float4 m1 = kmeta[k0 + 1];
            #pragma unroll
            for (int p = 0; p < 2; ++p) {
                float4 md = p ? m1 : m0;
                int c0 = __float_as_int(md.z);
                int re = 4 * j + 2 * p;         // even-g reg; odd is re+1
                #pragma unroll
                for (int tn = 0; tn < 4; ++tn) {
                    bool sel = (c0 >= anc[tn]);             // use column c0+1
                    float v = sel ? acc[tm][tn][re + 1] : acc[tm][tn][re];
                    float rj = sel ? md.y : md.x;
                    float logit = v * riv[tn] * rj;
                    pe[tn] += __expf(logit);
                    pc[tn] += (logit > pv[tn]) ? 1.f : 0.f;
                }
            }
        }
    }
    #pragma unroll
    for (int tn = 0; tn < 4; ++tn) {
        pe[tn] += __shfl_xor(pe[tn], 32);
        pc[tn] += __shfl_xor(pc[tn], 32);
        if (q == 0) {
            atomicAdd(&rowacc[anc[tn]], pe[tn]);
            atomicAdd(&rowacc[B_SZ + anc[tn]], pc[tn]);
        }
    }
}

// ---------------------------------------------------------------------------
// Kernel 3: tiny finalize — one thread per row, then block+global reduce.
// 32 blocks x 256 threads; reads only rowacc[2][8192] + pos_arr.
// ---------------------------------------------------------------------------
__global__ __launch_bounds__(256) void k_final(
    const float* __restrict__ rowacc, const float* __restrict__ pos_arr,
    float* __restrict__ out)
{
    int row = blockIdx.x * 256 + threadIdx.x;
    float pe = rowacc[row];
    float pc = rowacc[B_SZ + row];
    float pos = pos_arr[row];
    float loss = logf(__expf(pos) + pe) - pos;   // logsumexp - pos (logits bounded)
    float a1 = (pc < 0.5f) ? 1.f : 0.f;          // no neg strictly > pos
    float a5 = (pc < 4.5f) ? 1.f : 0.f;          // at most 4 negs strictly > pos
    for (int m = 1; m < 64; m <<= 1) {
        loss += __shfl_xor(loss, m);
        a1 += __shfl_xor(a1, m);
        a5 += __shfl_xor(a5, m);
    }
    __shared__ float red[3][4];
    int w = threadIdx.x >> 6, l = threadIdx.x & 63;
    if (l == 0) { red[0][w] = loss; red[1][w] = a1; red[2][w] = a5; }
    __syncthreads();
    if (threadIdx.x == 0) {
        float L = red[0][0] + red[0][1] + red[0][2] + red[0][3];
        float A1 = red[1][0] + red[1][1] + red[1][2] + red[1][3];
        float A5 = red[2][0] + red[2][1] + red[2][2] + red[2][3];
        atomicAdd(&out[0], L / (float)B_SZ);
        atomicAdd(&out[1], A1 * (100.f / (float)B_SZ));
        atomicAdd(&out[2], A5 * (100.f / (float)B_SZ));
    }
}

// ---------------------------------------------------------------------------
extern "C" void kernel_launch(void* const* d_in, const int* in_sizes, int n_in,
                              void* d_out, int out_size, void* d_ws, size_t ws_size,
                              hipStream_t stream)
{
    const float* zi = (const float*)d_in[0];
    const float* zj = (const float*)d_in[1];
    const int* perm = (const int*)d_in[2];
    float* out = (float*)d_out;

    // workspace layout (all 16B aligned)
    char* p = (char*)d_ws;
    unsigned char* A = (unsigned char*)p;    p += (size_t)B_SZ * D_SZ;          // 4 MB
    unsigned char* G = (unsigned char*)p;    p += (size_t)2 * K_SZ * D_SZ;      // 2 MB
    float* ri_arr = (float*)p;               p += (size_t)B_SZ * 4;
    float* pos_arr = (float*)p;              p += (size_t)B_SZ * 4;
    float4* kmeta = (float4*)p;              p += (size_t)K_SZ * 16;            // 32 KB
    float* rowacc = (float*)p;               p += (size_t)2 * B_SZ * 4;         // 64 KB

    k_prep<<<2048 + 1024, 256, 0, stream>>>(zi, zj, perm, ri_arr, pos_arr, A,
                                            kmeta, G, rowacc, out);
    k_gemm<<<512, 512, 0, stream>>>(A, G, kmeta, ri_arr, pos_arr, rowacc);
    k_final<<<32, 256, 0, stream>>>(rowacc, pos_arr, out);
}

// Round 4
// 49.830 us; speedup vs baseline: 1.0449x; 1.0018x over previous
//
#include <hip/hip_runtime.h>
#include <cstdint>

#define B_SZ 8192
#define D_SZ 512
#define K_SZ 2048
#define EPSV 1e-8f
// 1/TEMP
#define INV_T 2.0f

typedef float floatx16 __attribute__((ext_vector_type(16)));
typedef int intx8 __attribute__((ext_vector_type(8)));

// async global->LDS, 16B per lane. LDS dest must be wave-uniform base + lane*16.
__device__ __forceinline__ void async_cp16(const void* g, void* l) {
    typedef __attribute__((address_space(1))) unsigned int gds_t;
    typedef __attribute__((address_space(3))) unsigned int lds_t;
    __builtin_amdgcn_global_load_lds((gds_t*)(unsigned long long)g, (lds_t*)l, 16, 0, 0);
}

// pack 8 fp32 -> 8 fp8 e4m3 (OCP, RNE, saturating) as int2
__device__ __forceinline__ int2 pack_fp8x8(float4 a0, float4 a1) {
    int w0 = __builtin_amdgcn_cvt_pk_fp8_f32(a0.x, a0.y, 0, false);
    w0 = __builtin_amdgcn_cvt_pk_fp8_f32(a0.z, a0.w, w0, true);
    int w1 = __builtin_amdgcn_cvt_pk_fp8_f32(a1.x, a1.y, 0, false);
    w1 = __builtin_amdgcn_cvt_pk_fp8_f32(a1.z, a1.w, w1, true);
    return make_int2(w0, w1);
}

// ---------------------------------------------------------------------------
// Kernel 1 (merged prep+gather):
//  blocks [0,2048):  per-row norms of z_i/z_j, positive logit, z_i -> fp8 A.
//    Blocks [0,64) also zero rowacc[2][8192]; block 0 zeroes d_out.
//  blocks [2048,3072): SORTED gather. Block bg handles k0=2bg, k0+1.
//    rank(c0) = #{perm[j] < c0} (distinct values -> bijective rank onto
//    [0,2048)). Wave w: k = k0 + (w>>1), variant vv = w&1, row c = c0+vv.
//    Writes G[vv][rank] = fp8(zj[c]) and meta[vv][rank] = {1/nj(c), c0}.
//    Sorting is free semantically: negatives only feed a sum of exp.
// ---------------------------------------------------------------------------
__global__ __launch_bounds__(256) void k_prep(
    const float* __restrict__ zi, const float* __restrict__ zj,
    const int* __restrict__ perm,
    float* __restrict__ ri_arr, float* __restrict__ pos_arr,
    unsigned char* __restrict__ A,
    float2* __restrict__ meta, unsigned char* __restrict__ G,
    float* __restrict__ rowacc, float* __restrict__ out)
{
    int w = threadIdx.x >> 6, l = threadIdx.x & 63;
    if (blockIdx.x < 2048) {
        if (blockIdx.x < 64)
            rowacc[blockIdx.x * 256 + threadIdx.x] = 0.f;   // pe[8192] ++ pc[8192]
        if (blockIdx.x == 0 && threadIdx.x < 3) out[threadIdx.x] = 0.f;
        int row = blockIdx.x * 4 + w;
        const float4* zi4 = (const float4*)(zi + (size_t)row * D_SZ);
        const float4* zj4 = (const float4*)(zj + (size_t)row * D_SZ);
        float4 a0 = zi4[2 * l], a1 = zi4[2 * l + 1];
        float4 b0 = zj4[2 * l], b1 = zj4[2 * l + 1];
        float si = a0.x * a0.x + a0.y * a0.y + a0.z * a0.z + a0.w * a0.w
                 + a1.x * a1.x + a1.y * a1.y + a1.z * a1.z + a1.w * a1.w;
        float sj = b0.x * b0.x + b0.y * b0.y + b0.z * b0.z + b0.w * b0.w
                 + b1.x * b1.x + b1.y * b1.y + b1.z * b1.z + b1.w * b1.w;
        float dd = a0.x * b0.x + a0.y * b0.y + a0.z * b0.z + a0.w * b0.w
                 + a1.x * b1.x + a1.y * b1.y + a1.z * b1.z + a1.w * b1.w;
        for (int m = 1; m < 64; m <<= 1) {
            si += __shfl_xor(si, m);
            sj += __shfl_xor(sj, m);
            dd += __shfl_xor(dd, m);
        }
        if (l == 0) {
            float ni = sqrtf(si), nj = sqrtf(sj);
            ri_arr[row] = INV_T / fmaxf(ni, 1e-6f);   // norms ~22; eps never binds
            pos_arr[row] = dd / fmaxf(ni * nj, EPSV) * INV_T;
        }
        *(int2*)(A + (size_t)row * D_SZ + l * 8) = pack_fp8x8(a0, a1);
    } else {
        __shared__ int rpart[2][4];
        int bg = blockIdx.x - 2048;                 // 0..1023
        int k0 = bg * 2;
        int c0a = perm[k0], c0b = perm[k0 + 1];
        // rank pass: count sampled values < c0 (perm is 8 KB, L1/L2-hot)
        int cnta = 0, cntb = 0;
        for (int j = threadIdx.x; j < K_SZ; j += 256) {
            int p = perm[j];
            cnta += (p < c0a) ? 1 : 0;
            cntb += (p < c0b) ? 1 : 0;
        }
        for (int m = 1; m < 64; m <<= 1) {
            cnta += __shfl_xor(cnta, m);
            cntb += __shfl_xor(cntb, m);
        }
        if (l == 0) { rpart[0][w] = cnta; rpart[1][w] = cntb; }
        __syncthreads();
        int ra = rpart[0][0] + rpart[0][1] + rpart[0][2] + rpart[0][3];
        int rb = rpart[1][0] + rpart[1][1] + rpart[1][2] + rpart[1][3];
        int myc0   = (w >> 1) ? c0b : c0a;
        int myrank = (w >> 1) ? rb : ra;
        int vv = w & 1;
        int c = myc0 + vv;                          // actual z_j row
        const float4* src = (const float4*)(zj + (size_t)c * D_SZ);
        float4 a0 = src[2 * l], a1 = src[2 * l + 1];
        float s = a0.x * a0.x + a0.y * a0.y + a0.z * a0.z + a0.w * a0.w
                + a1.x * a1.x + a1.y * a1.y + a1.z * a1.z + a1.w * a1.w;
        for (int m = 1; m < 64; m <<= 1) s += __shfl_xor(s, m);
        if (l == 0) {
            float rj = 1.0f / fmaxf(sqrtf(s), 1e-6f);
            meta[vv * K_SZ + myrank] = make_float2(rj, __int_as_float(myc0));
        }
        *(int2*)(G + ((size_t)(vv * K_SZ + myrank)) * D_SZ + l * 8) =
            pack_fp8x8(a0, a1);
    }
}

// ---------------------------------------------------------------------------
// Kernel 2: MX-fp8 MFMA GEMM, TRANSPOSED OUTPUT: S^T = G_v . A^T.
// R4: revert to the verified R0 structure (128x128 tile, 256 thr, 2x2 waves,
// BK=64, dbuf LDS 2x(8+8) KB, 16B-chunk XOR swizzle, 4 blocks/CU) -- the
// best-measured schedule for this skinny-K (512) GEMM. NEW: sorted variant
// split. G holds two sorted 2048x512 matrices (LO: rows sc[k], HI: rows
// sc[k]+1). Because sc is sorted, the include mask (LO: c0<i, HI: c0>=i)
// is a monotone staircase -> a 128x128 tile is all-LO, all-HI, or mixed.
// Grid 2048 = 16 gTiles x 64 aTiles x 2 variants; ~47% of blocks early-exit
// after one meta read (work 34.4 -> ~19.5 GFLOP). Epilogue: per-element
// include mask instead of pair-select; exactly one variant fires per (k,i),
// diagonal (col==i) never selected -> reference semantics preserved.
// bids b,b+8 = (LO,HI) of same tile -> same XCD, shared A-panel in L2.
// ---------------------------------------------------------------------------
__global__ __launch_bounds__(256, 4) void k_gemm(
    const unsigned char* __restrict__ A,    // [8192][512] fp8  (anchors)
    const unsigned char* __restrict__ G,    // [2][2048][512] fp8 sorted gather
    const float2* __restrict__ meta,        // [2][2048]  {rj, c0 bits}
    const float* __restrict__ ri_arr,       // [8192]  INV_T/ni
    const float* __restrict__ pos_arr,      // [8192]
    float* __restrict__ rowacc)             // [2][8192] atomic accumulators
{
    const int bid = blockIdx.x;
    const int xcd = bid & 7;                // HW XCD round-robin period 8
    const int rest = bid >> 3;              // 0..255
    const int v = rest & 1;                 // 0 = LO (c0 < i), 1 = HI (c0 >= i)
    const int slot = rest >> 1;             // 0..127
    const int gTile = xcd * 2 + (slot & 1); // 0..15 (G row panel, per variant)
    const int aTile = slot >> 1;            // 0..63 (anchor panel)
    const int gBase = gTile * 128;          // row in variant's 2048
    const int aBase = aTile * 128;
    const float2* mv = meta + v * K_SZ;

    // ---- early exit: tile intersects this variant's staircase region? ----
    if (v == 0) {
        // need some i in [aBase, aBase+128) with c0 < i; min c0 = sc[gBase]
        int c0min = __float_as_int(mv[gBase].y);
        if (c0min >= aBase + 127) return;
    } else {
        // need some i with c0 >= i; max c0 = sc[gBase+127]
        int c0max = __float_as_int(mv[gBase + 127].y);
        if (c0max < aBase) return;
    }

    __shared__ unsigned char Asl[2][128 * 64];   // anchor tile, 8 KB per buffer
    __shared__ unsigned char Gsl[2][128 * 64];   // g tile
    const int tid = threadIdx.x;
    const int l = tid & 63, w = tid >> 6;
    const int wm = w >> 1, wn = w & 1;      // wm: g-half, wn: anchor-half
    const int ln = l & 31, q = l >> 5;      // 32x32 MFMA lane decomposition

    // staging offsets (bytes); 512 16B-chunks per array per dblk (2 iters x 256)
    size_t aOff[2], gOff[2];
    int ldsOff[2];
    #pragma unroll
    for (int it = 0; it < 2; ++it) {
        int fc = it * 256 + tid;            // 16B chunk 0..511
        int r = fc >> 2, s = fc & 3;
        int scc = s ^ ((r ^ (r >> 2)) & 3); // XOR swizzle source 16B chunk
        aOff[it] = (size_t)(aBase + r) * D_SZ + scc * 16;
        gOff[it] = (size_t)(v * K_SZ + gBase + r) * D_SZ + scc * 16;
        ldsOff[it] = fc * 16;
    }

    floatx16 acc[2][2] = {};                // [tm: g-subtile][tn: anchor-subtile]

    // frag read addresses (bytes in an 8 KB buffer): lane needs k-bytes
    // [q*32, q*32+32) of its row = pre-swizzle chunks {2q, 2q+1}
    int aAddr[2][2], gAddr[2][2];           // [t][chunk half]
    #pragma unroll
    for (int t = 0; t < 2; ++t) {
        int ar = wn * 64 + t * 32 + ln;     // anchor row (N-operand)
        int xa = (ar ^ (ar >> 2)) & 3;
        aAddr[t][0] = ar * 64 + ((2 * q) ^ xa) * 16;
        aAddr[t][1] = ar * 64 + ((2 * q + 1) ^ xa) * 16;
        int gr = wm * 64 + t * 32 + ln;     // g row (M-operand)
        int xg = (gr ^ (gr >> 2)) & 3;
        gAddr[t][0] = gr * 64 + ((2 * q) ^ xg) * 16;
        gAddr[t][1] = gr * 64 + ((2 * q + 1) ^ xg) * 16;
    }

    // prologue: stage k-block 0 into buffer 0
    #pragma unroll
    for (int it = 0; it < 2; ++it) {
        async_cp16(A + aOff[it], &Asl[0][ldsOff[it]]);
        async_cp16(G + gOff[it], &Gsl[0][ldsOff[it]]);
    }

    #pragma unroll 1
    for (int dblk = 0; dblk < 8; ++dblk) {
        const int cur = dblk & 1, nxt = cur ^ 1;
        __syncthreads();                    // staged data for `cur` is ready
        if (dblk < 7) {
            #pragma unroll
            for (int it = 0; it < 2; ++it) {
                async_cp16(A + aOff[it] + (size_t)(dblk + 1) * 64, &Asl[nxt][ldsOff[it]]);
                async_cp16(G + gOff[it] + (size_t)(dblk + 1) * 64, &Gsl[nxt][ldsOff[it]]);
            }
        }
        intx8 af[2], gf[2];
        #pragma unroll
        for (int t = 0; t < 2; ++t) {
            int4 lo = *(const int4*)&Asl[cur][aAddr[t][0]];
            int4 hi = *(const int4*)&Asl[cur][aAddr[t][1]];
            af[t][0] = lo.x; af[t][1] = lo.y; af[t][2] = lo.z; af[t][3] = lo.w;
            af[t][4] = hi.x; af[t][5] = hi.y; af[t][6] = hi.z; af[t][7] = hi.w;
            int4 glo = *(const int4*)&Gsl[cur][gAddr[t][0]];
            int4 ghi = *(const int4*)&Gsl[cur][gAddr[t][1]];
            gf[t][0] = glo.x; gf[t][1] = glo.y; gf[t][2] = glo.z; gf[t][3] = glo.w;
            gf[t][4] = ghi.x; gf[t][5] = ghi.y; gf[t][6] = ghi.z; gf[t][7] = ghi.w;
        }
        #pragma unroll
        for (int tm = 0; tm < 2; ++tm)
            #pragma unroll
            for (int tn = 0; tn < 2; ++tn)
                acc[tm][tn] = __builtin_amdgcn_mfma_scale_f32_32x32x64_f8f6f4(
                    gf[tm], af[tn], acc[tm][tn],
                    0, 0,                       // cbsz/blgp = fp8 e4m3
                    0, 0x7f7f7f7f,              // scale A: all-ones (2^0)
                    0, 0x7f7f7f7f);             // scale B: all-ones (2^0)
    }

    // ---- fused epilogue: include-mask, in-register reduction ----
    // C/D layout (32x32): col = anchor = ln (+tn*32), row = g = (reg&3) +
    // 8*(reg>>2) + 4*q (+tm*32 + wm*64). k = gBase + row (sorted index).
    // include: LO -> c0 < i; HI -> c0 >= i. Exactly one variant fires per
    // (k,i); the diagonal column (==i) is never selected.
    int anc[2]; float riv[2], pv[2], pe[2] = {0.f, 0.f}, pc[2] = {0.f, 0.f};
    #pragma unroll
    for (int tn = 0; tn < 2; ++tn) {
        anc[tn] = aBase + wn * 64 + tn * 32 + ln;
        riv[tn] = ri_arr[anc[tn]];          // INV_T / ni
        pv[tn] = pos_arr[anc[tn]];
    }
    #pragma unroll
    for (int tm = 0; tm < 2; ++tm) {
        #pragma unroll
        for (int j = 0; j < 4; ++j) {
            #pragma unroll
            for (int b = 0; b < 4; ++b) {
                int re = 4 * j + b;
                int k = gBase + wm * 64 + tm * 32 + 4 * q + b + 8 * j;
                float2 md = mv[k];
                float rj = md.x;
                int c0 = __float_as_int(md.y);
                #pragma unroll
                for (int tn = 0; tn < 2; ++tn) {
                    bool inc = v ? (c0 >= anc[tn]) : (c0 < anc[tn]);
                    float logit = acc[tm][tn][re] * riv[tn] * rj;
                    pe[tn] += inc ? __expf(logit) : 0.f;
                    pc[tn] += (inc && logit > pv[tn]) ? 1.f : 0.f;
                }
            }
        }
    }
    #pragma unroll
    for (int tn = 0; tn < 2; ++tn) {
        pe[tn] += __shfl_xor(pe[tn], 32);
        pc[tn] += __shfl_xor(pc[tn], 32);
        if (q == 0) {
            atomicAdd(&rowacc[anc[tn]], pe[tn]);
            atomicAdd(&rowacc[B_SZ + anc[tn]], pc[tn]);
        }
    }
}

// ---------------------------------------------------------------------------
// Kernel 3: tiny finalize — one thread per row, then block+global reduce.
// 32 blocks x 256 threads; reads only rowacc[2][8192] + pos_arr.
// ---------------------------------------------------------------------------
__global__ __launch_bounds__(256) void k_final(
    const float* __restrict__ rowacc, const float* __restrict__ pos_arr,
    float* __restrict__ out)
{
    int row = blockIdx.x * 256 + threadIdx.x;
    float pe = rowacc[row];
    float pc = rowacc[B_SZ + row];
    float pos = pos_arr[row];
    float loss = logf(__expf(pos) + pe) - pos;   // logsumexp - pos (logits bounded)
    float a1 = (pc < 0.5f) ? 1.f : 0.f;          // no neg strictly > pos
    float a5 = (pc < 4.5f) ? 1.f : 0.f;          // at most 4 negs strictly > pos
    for (int m = 1; m < 64; m <<= 1) {
        loss += __shfl_xor(loss, m);
        a1 += __shfl_xor(a1, m);
        a5 += __shfl_xor(a5, m);
    }
    __shared__ float red[3][4];
    int w = threadIdx.x >> 6, l = threadIdx.x & 63;
    if (l == 0) { red[0][w] = loss; red[1][w] = a1; red[2][w] = a5; }
    __syncthreads();
    if (threadIdx.x == 0) {
        float L = red[0][0] + red[0][1] + red[0][2] + red[0][3];
        float A1 = red[1][0] + red[1][1] + red[1][2] + red[1][3];
        float A5 = red[2][0] + red[2][1] + red[2][2] + red[2][3];
        atomicAdd(&out[0], L / (float)B_SZ);
        atomicAdd(&out[1], A1 * (100.f / (float)B_SZ));
        atomicAdd(&out[2], A5 * (100.f / (float)B_SZ));
    }
}

// ---------------------------------------------------------------------------
extern "C" void kernel_launch(void* const* d_in, const int* in_sizes, int n_in,
                              void* d_out, int out_size, void* d_ws, size_t ws_size,
                              hipStream_t stream)
{
    const float* zi = (const float*)d_in[0];
    const float* zj = (const float*)d_in[1];
    const int* perm = (const int*)d_in[2];
    float* out = (float*)d_out;

    // workspace layout (all 16B aligned)
    char* p = (char*)d_ws;
    unsigned char* A = (unsigned char*)p;    p += (size_t)B_SZ * D_SZ;          // 4 MB
    unsigned char* G = (unsigned char*)p;    p += (size_t)2 * K_SZ * D_SZ;      // 2 MB
    float* ri_arr = (float*)p;               p += (size_t)B_SZ * 4;
    float* pos_arr = (float*)p;              p += (size_t)B_SZ * 4;
    float2* meta = (float2*)p;               p += (size_t)2 * K_SZ * 8;         // 32 KB
    float* rowacc = (float*)p;               p += (size_t)2 * B_SZ * 4;         // 64 KB

    k_prep<<<2048 + 1024, 256, 0, stream>>>(zi, zj, perm, ri_arr, pos_arr, A,
                                            meta, G, rowacc, out);
    k_gemm<<<2048, 256, 0, stream>>>(A, G, meta, ri_arr, pos_arr, rowacc);
    k_final<<<32, 256, 0, stream>>>(rowacc, pos_arr, out);
}